// Round 1
// baseline (2698.846 us; speedup 1.0000x reference)
//
#include <hip/hip_runtime.h>

// Shapes (fixed by the reference):
//   x: (16, 64, 256, 256) f32; conv_w: (64,64,3,3); conv_b/gamma/beta: (64,)
//   out: (16, 128, 256, 256) f32  -> channels 0..63 = a, 64..127 = block-sorted a
// Workspace layout (tiny): ws[0..128) = stats (sum[64], sumsq[64]),
//                          ws[128..128+36864) = transposed weights [ci][tap][cout]

#define HH 256
#define WW 256
#define NPIX 65536           // 256*256
#define M_ELEMS 1048576.0f   // 16*256*256 per channel

// ---------------- K0: zero stats + transpose weights ----------------
__global__ __launch_bounds__(256) void prep_kernel(const float* __restrict__ w,
                                                   float* __restrict__ ws) {
  int idx = blockIdx.x * 256 + threadIdx.x;
  if (idx < 128) ws[idx] = 0.0f;
  if (idx < 64 * 9 * 64) {
    int o   = idx & 63;       // c_out
    int rem = idx >> 6;       // ci*9 + tap
    int tap = rem % 9;
    int i   = rem / 9;        // c_in
    ws[128 + idx] = w[(o * 64 + i) * 9 + tap];
  }
}

// ---------------- K1: dilated conv + bias -> out[a region] ----------------
// Block: 256 threads; tile 16x16 output pixels, all 64 c_out, one n.
// Each thread: 2 adjacent pixels x 32 output channels = 64 accumulators.
// LDS: input chunk 16ch x 20x20 (25.6 KB) + weights 16x9x64 (36.9 KB).
__global__ __launch_bounds__(256) void conv_kernel(const float* __restrict__ x,
                                                   const float* __restrict__ wT,
                                                   const float* __restrict__ bias,
                                                   float* __restrict__ out) {
  __shared__ float sIn[16 * 20 * 20];
  __shared__ float sW[16 * 9 * 64];

  const int t  = threadIdx.x;
  const int w0 = blockIdx.x * 16;
  const int h0 = blockIdx.y * 16;
  const int n  = blockIdx.z;

  const int cg  = t >> 7;            // 0 or 1 -> c_out half
  const int p0  = (t & 127) * 2;     // pixel pair id in 16x16 tile
  const int py  = p0 >> 4;
  const int px0 = p0 & 15;           // even

  float acc0[32], acc1[32];
#pragma unroll
  for (int i = 0; i < 32; ++i) { acc0[i] = 0.0f; acc1[i] = 0.0f; }

  for (int chunk = 0; chunk < 4; ++chunk) {
    __syncthreads();
    const int cibase = chunk * 16;
    // stage input tile (zero-padded)
    for (int idx = t; idx < 6400; idx += 256) {
      int ci  = idx / 400;
      int rem = idx % 400;
      int ty  = rem / 20;
      int tx  = rem % 20;
      int h = h0 + ty - 2;
      int w = w0 + tx - 2;
      float v = 0.0f;
      if ((unsigned)h < 256u && (unsigned)w < 256u)
        v = x[((n * 64 + cibase + ci) * 256 + h) * 256 + w];
      sIn[idx] = v;
    }
    // stage weights (contiguous copy thanks to pre-transpose)
    const float* wsrc = wT + cibase * 576;
    for (int idx = t; idx < 9216; idx += 256) sW[idx] = wsrc[idx];
    __syncthreads();

    for (int ci = 0; ci < 16; ++ci) {
#pragma unroll
      for (int tap = 0; tap < 9; ++tap) {
        const int dy = (tap / 3) * 2;
        const int dx = (tap % 3) * 2;
        const int ib = ci * 400 + (py + dy) * 20 + (px0 + dx);
        float in0 = sIn[ib];
        float in1 = sIn[ib + 1];
        const float4* w4 =
            reinterpret_cast<const float4*>(&sW[(ci * 9 + tap) * 64 + cg * 32]);
#pragma unroll
        for (int q = 0; q < 8; ++q) {
          float4 ww = w4[q];
          acc0[q * 4 + 0] += in0 * ww.x; acc1[q * 4 + 0] += in1 * ww.x;
          acc0[q * 4 + 1] += in0 * ww.y; acc1[q * 4 + 1] += in1 * ww.y;
          acc0[q * 4 + 2] += in0 * ww.z; acc1[q * 4 + 2] += in1 * ww.z;
          acc0[q * 4 + 3] += in0 * ww.w; acc1[q * 4 + 3] += in1 * ww.w;
        }
      }
    }
  }

  // epilogue: +bias, write to a-region of out
  const int cbase = cg * 32;
  const int h = h0 + py;
  const int w = w0 + px0;
#pragma unroll
  for (int co = 0; co < 32; ++co) {
    int c = cbase + co;
    float b = bias[c];
    float2 v;
    v.x = acc0[co] + b;
    v.y = acc1[co] + b;
    *reinterpret_cast<float2*>(&out[((n * 128 + c) * NPIX) + h * 256 + w]) = v;
  }
}

// ---------------- K2: per-channel sum / sumsq over a-region ----------------
__global__ __launch_bounds__(256) void stats_kernel(const float* __restrict__ convOut,
                                                    float* __restrict__ stats) {
  const int c    = blockIdx.x >> 5;   // 64 channels
  const int part = blockIdx.x & 31;   // 32 parts per channel
  const int n    = part >> 1;
  const int half = part & 1;
  const float* base = convOut + ((size_t)(n * 128 + c)) * NPIX + half * 32768;

  float s = 0.0f, sq = 0.0f;
#pragma unroll 4
  for (int i = 0; i < 32; ++i) {
    float4 v = *reinterpret_cast<const float4*>(base + i * 1024 + threadIdx.x * 4);
    s  += v.x + v.y + v.z + v.w;
    sq += v.x * v.x + v.y * v.y + v.z * v.z + v.w * v.w;
  }
#pragma unroll
  for (int off = 32; off > 0; off >>= 1) {
    s  += __shfl_down(s, off);
    sq += __shfl_down(sq, off);
  }
  __shared__ float ls[4], lq[4];
  int wid = threadIdx.x >> 6, lane = threadIdx.x & 63;
  if (lane == 0) { ls[wid] = s; lq[wid] = sq; }
  __syncthreads();
  if (threadIdx.x == 0) {
    float S = ls[0] + ls[1] + ls[2] + ls[3];
    float Q = lq[0] + lq[1] + lq[2] + lq[3];
    atomicAdd(&stats[c], S);
    atomicAdd(&stats[64 + c], Q);
  }
}

// ---------------- K3: BN + ReLU (in place) + 4x4 block sort -> y ----------------
__global__ __launch_bounds__(256) void bn_sort_kernel(const float* __restrict__ stats,
                                                      const float* __restrict__ gamma,
                                                      const float* __restrict__ beta,
                                                      float* __restrict__ out) {
  const int c = blockIdx.y;
  const int n = blockIdx.z;
  const int t = threadIdx.x;
  const int bx = t & 63;
  const int by = blockIdx.x * 4 + (t >> 6);

  const float mean = stats[c] / M_ELEMS;
  const float var  = stats[64 + c] / M_ELEMS - mean * mean;
  const float inv  = rsqrtf(var + 1e-5f);
  const float g    = gamma[c] * inv;
  const float bb   = beta[c] - mean * g;

  const int base = ((n * 128 + c) * NPIX) + (by * 4) * 256 + bx * 4;

  float v[16];
#pragma unroll
  for (int r = 0; r < 4; ++r) {
    float4 q = *reinterpret_cast<const float4*>(&out[base + r * 256]);
    v[r * 4 + 0] = fmaxf(q.x * g + bb, 0.0f);
    v[r * 4 + 1] = fmaxf(q.y * g + bb, 0.0f);
    v[r * 4 + 2] = fmaxf(q.z * g + bb, 0.0f);
    v[r * 4 + 3] = fmaxf(q.w * g + bb, 0.0f);
  }
  // write a back in place
#pragma unroll
  for (int r = 0; r < 4; ++r) {
    float4 q;
    q.x = v[r * 4 + 0]; q.y = v[r * 4 + 1]; q.z = v[r * 4 + 2]; q.w = v[r * 4 + 3];
    *reinterpret_cast<float4*>(&out[base + r * 256]) = q;
  }
  // bitonic sort of 16 values (ascending), fully unrolled -> registers
#pragma unroll
  for (int k = 2; k <= 16; k <<= 1) {
#pragma unroll
    for (int j = k >> 1; j > 0; j >>= 1) {
#pragma unroll
      for (int i = 0; i < 16; ++i) {
        int l = i ^ j;
        if (l > i) {
          bool up = ((i & k) == 0);
          float a = v[i], b = v[l];
          float mn = fminf(a, b), mx = fmaxf(a, b);
          v[i] = up ? mn : mx;
          v[l] = up ? mx : mn;
        }
      }
    }
  }
  const int ybase = base + 64 * NPIX;
#pragma unroll
  for (int r = 0; r < 4; ++r) {
    float4 q;
    q.x = v[r * 4 + 0]; q.y = v[r * 4 + 1]; q.z = v[r * 4 + 2]; q.w = v[r * 4 + 3];
    *reinterpret_cast<float4*>(&out[ybase + r * 256]) = q;
  }
}

extern "C" void kernel_launch(void* const* d_in, const int* in_sizes, int n_in,
                              void* d_out, int out_size, void* d_ws, size_t ws_size,
                              hipStream_t stream) {
  const float* x      = (const float*)d_in[0];
  const float* conv_w = (const float*)d_in[1];
  const float* conv_b = (const float*)d_in[2];
  const float* gamma  = (const float*)d_in[3];
  const float* beta   = (const float*)d_in[4];
  float* out   = (float*)d_out;
  float* ws    = (float*)d_ws;
  float* stats = ws;
  const float* wT = ws + 128;

  hipLaunchKernelGGL(prep_kernel, dim3(145), dim3(256), 0, stream, conv_w, ws);
  hipLaunchKernelGGL(conv_kernel, dim3(16, 16, 16), dim3(256), 0, stream,
                     x, wT, conv_b, out);
  hipLaunchKernelGGL(stats_kernel, dim3(2048), dim3(256), 0, stream, out, stats);
  hipLaunchKernelGGL(bn_sort_kernel, dim3(16, 64, 16), dim3(256), 0, stream,
                     stats, gamma, beta, out);
}

// Round 2
// 986.243 us; speedup vs baseline: 2.7365x; 2.7365x over previous
//
#include <hip/hip_runtime.h>

// x: (16,64,256,256) f32; conv_w: (64,64,3,3); conv_b/gamma/beta: (64,)
// out: (16,128,256,256) f32 -> ch 0..63 = a (BN+ReLU of conv), 64..127 = 4x4-block-sorted a
//
// ws layout (floats): [0,128)   = stats (sum[64], sumsq[64])
//                     [128,..)  = W' bf16 as ushort[64*576], k = tap*64+ci  (73728 B)
//                     [18560,..) = per-block stat partials [4096][128] (2 MB, optional)

typedef __attribute__((ext_vector_type(8))) short short8;
typedef __attribute__((ext_vector_type(4))) float f32x4;

#define NPIX 65536
#define M_ELEMS 1048576.0f
#define PARTIAL_OFF 18560
#define NBLK 4096

__device__ __forceinline__ unsigned short f2bf(float f) {
  unsigned u = __builtin_bit_cast(unsigned, f);
  u = (u + 0x7fffu + ((u >> 16) & 1u)) >> 16;
  return (unsigned short)u;
}

// ---------------- K0: zero stats + build W' bf16 [cout][tap*64+ci] ----------------
__global__ __launch_bounds__(256) void prep_kernel(const float* __restrict__ w,
                                                   float* __restrict__ ws) {
  int idx = blockIdx.x * 256 + threadIdx.x;
  if (idx < 128) ws[idx] = 0.0f;
  if (idx < 36864) {
    int cout = idx / 576;
    int k    = idx % 576;
    int tap  = k >> 6;
    int ci   = k & 63;
    unsigned short* wbf = (unsigned short*)(ws + 128);
    wbf[idx] = f2bf(w[(cout * 64 + ci) * 9 + tap]);
  }
}

// ---------------- K1: implicit-GEMM MFMA conv + bias + fused stats ----------------
// 256 thr = 4 waves. Tile: 16x16 pixels, all 64 couts. Wave: 32 couts x 8 rows.
// LDS X: [pix 20*20][ci 64] bf16, ci-block XOR-swizzled by (pix&7).
__global__ __launch_bounds__(256, 2) void conv_mfma_kernel(
    const float* __restrict__ x, const unsigned short* __restrict__ wbf,
    const float* __restrict__ bias, float* __restrict__ out,
    float* __restrict__ partial, float* __restrict__ stats) {
  __shared__ short sX[400 * 64];   // 51200 B
  __shared__ float sRed[2][128];

  const int t    = threadIdx.x;
  const int lane = t & 63;
  const int wv   = t >> 6;
  const int g    = lane >> 4;      // k-group (MFMA lane>>4)
  const int px   = lane & 15;      // pixel col / A row
  const int n    = blockIdx.z;
  const int h0   = blockIdx.y * 16;
  const int w0   = blockIdx.x * 16;

  const int cbase  = (wv & 1) * 32;   // cout base for this wave (2 tiles of 16)
  const int pybase = (wv >> 1) * 8;   // 8 pixel rows per wave

  // ---- A fragments in registers: 2 cout tiles x 18 k-steps (144 VGPR) ----
  short8 a0[18], a1[18];
  {
    const unsigned short* r0 = wbf + (cbase + px) * 576 + g * 8;
    const unsigned short* r1 = r0 + 16 * 576;
#pragma unroll
    for (int s = 0; s < 18; ++s) {
      a0[s] = *reinterpret_cast<const short8*>(r0 + s * 32);
      a1[s] = *reinterpret_cast<const short8*>(r1 + s * 32);
    }
  }

  // ---- stage X tile (zero-padded halo) into LDS as bf16, swizzled ----
  for (int cg = 0; cg < 8; ++cg) {
    const float* xc = x + (size_t)(n * 64 + cg * 8) * NPIX;
#pragma unroll
    for (int b = 0; b < 2; ++b) {
      int pix = b * 256 + t;
      if (pix < 400) {
        int hy = pix / 20, hx = pix - hy * 20;
        int h = h0 + hy - 2, w = w0 + hx - 2;
        short8 pk;
        if ((unsigned)h < 256u && (unsigned)w < 256u) {
          const float* xp = xc + h * 256 + w;
#pragma unroll
          for (int j = 0; j < 8; ++j) pk[j] = (short)f2bf(xp[j * NPIX]);
        } else {
#pragma unroll
          for (int j = 0; j < 8; ++j) pk[j] = 0;
        }
        int blkS = cg ^ (pix & 7);
        *reinterpret_cast<short8*>(&sX[pix * 64 + blkS * 8]) = pk;
      }
    }
  }
  __syncthreads();

  float b0[4], b1[4];
#pragma unroll
  for (int i = 0; i < 4; ++i) {
    b0[i] = bias[cbase + g * 4 + i];
    b1[i] = bias[cbase + 16 + g * 4 + i];
  }
  float lsum[8] = {0, 0, 0, 0, 0, 0, 0, 0};
  float lsq[8]  = {0, 0, 0, 0, 0, 0, 0, 0};

  for (int py8 = 0; py8 < 8; ++py8) {
    const int py = pybase + py8;
    f32x4 acc0 = {0.f, 0.f, 0.f, 0.f};
    f32x4 acc1 = {0.f, 0.f, 0.f, 0.f};
#pragma unroll
    for (int s = 0; s < 18; ++s) {
      const int tap = s >> 1;
      const int dy = (tap / 3) * 2, dx = (tap % 3) * 2;
      int pix = (py + dy) * 20 + px + dx;
      int blk = ((s & 1) * 4 + g) ^ (pix & 7);
      short8 bf = *reinterpret_cast<const short8*>(&sX[pix * 64 + blk * 8]);
      acc0 = __builtin_amdgcn_mfma_f32_16x16x32_bf16(a0[s], bf, acc0, 0, 0, 0);
      acc1 = __builtin_amdgcn_mfma_f32_16x16x32_bf16(a1[s], bf, acc1, 0, 0, 0);
    }
    // C/D layout: col = lane&15 (pixel), row = (lane>>4)*4 + i (cout in tile)
    const int h = h0 + py, wo = w0 + px;
    float* obase = out + (size_t)(n * 128) * NPIX + h * 256 + wo;
#pragma unroll
    for (int i = 0; i < 4; ++i) {
      float v0 = acc0[i] + b0[i];
      float v1 = acc1[i] + b1[i];
      obase[(cbase + g * 4 + i) * NPIX] = v0;
      obase[(cbase + 16 + g * 4 + i) * NPIX] = v1;
      lsum[i] += v0;     lsq[i] += v0 * v0;
      lsum[4 + i] += v1; lsq[4 + i] += v1 * v1;
    }
  }

  // ---- fused stats: reduce across the 16 lanes sharing the same couts ----
#pragma unroll
  for (int m = 1; m < 16; m <<= 1) {
#pragma unroll
    for (int k = 0; k < 8; ++k) {
      lsum[k] += __shfl_xor(lsum[k], m);
      lsq[k]  += __shfl_xor(lsq[k], m);
    }
  }
  const int ph = wv >> 1;
  if ((lane & 15) == 0) {
#pragma unroll
    for (int i = 0; i < 4; ++i) {
      int c0 = cbase + g * 4 + i, c1 = c0 + 16;
      sRed[ph][c0] = lsum[i];     sRed[ph][64 + c0] = lsq[i];
      sRed[ph][c1] = lsum[4 + i]; sRed[ph][64 + c1] = lsq[4 + i];
    }
  }
  __syncthreads();
  if (t < 128) {
    float v = sRed[0][t] + sRed[1][t];
    if (partial) {
      int bid = (blockIdx.z * 16 + blockIdx.y) * 16 + blockIdx.x;
      partial[bid * 128 + t] = v;
    } else {
      atomicAdd(&stats[t], v);
    }
  }
}

// ---------------- K2a: reduce per-block partials -> stats ----------------
__global__ __launch_bounds__(256) void reduce_stats_kernel(const float* __restrict__ partial,
                                                           float* __restrict__ stats) {
  const int c = blockIdx.x;   // 0..127
  const int t = threadIdx.x;
  float s = 0.f;
#pragma unroll
  for (int k = 0; k < 16; ++k) s += partial[(size_t)(k * 256 + t) * 128 + c];
#pragma unroll
  for (int m = 32; m > 0; m >>= 1) s += __shfl_down(s, m);
  __shared__ float ls[4];
  if ((t & 63) == 0) ls[t >> 6] = s;
  __syncthreads();
  if (t == 0) stats[c] = ls[0] + ls[1] + ls[2] + ls[3];
}

// ---------------- K2b fallback: per-channel sum/sumsq over a-region ----------------
__global__ __launch_bounds__(256) void stats_kernel(const float* __restrict__ convOut,
                                                    float* __restrict__ stats) {
  const int c    = blockIdx.x >> 5;
  const int part = blockIdx.x & 31;
  const int n    = part >> 1;
  const int half = part & 1;
  const float* base = convOut + ((size_t)(n * 128 + c)) * NPIX + half * 32768;
  float s = 0.0f, sq = 0.0f;
#pragma unroll 4
  for (int i = 0; i < 32; ++i) {
    float4 v = *reinterpret_cast<const float4*>(base + i * 1024 + threadIdx.x * 4);
    s  += v.x + v.y + v.z + v.w;
    sq += v.x * v.x + v.y * v.y + v.z * v.z + v.w * v.w;
  }
#pragma unroll
  for (int off = 32; off > 0; off >>= 1) {
    s  += __shfl_down(s, off);
    sq += __shfl_down(sq, off);
  }
  __shared__ float ls[4], lq[4];
  int wid = threadIdx.x >> 6, lane = threadIdx.x & 63;
  if (lane == 0) { ls[wid] = s; lq[wid] = sq; }
  __syncthreads();
  if (threadIdx.x == 0) {
    atomicAdd(&stats[c], ls[0] + ls[1] + ls[2] + ls[3]);
    atomicAdd(&stats[64 + c], lq[0] + lq[1] + lq[2] + lq[3]);
  }
}

// ---------------- K3: BN + ReLU (in place) + 4x4 block sort -> y ----------------
__global__ __launch_bounds__(256) void bn_sort_kernel(const float* __restrict__ stats,
                                                      const float* __restrict__ gamma,
                                                      const float* __restrict__ beta,
                                                      float* __restrict__ out) {
  const int c = blockIdx.y;
  const int n = blockIdx.z;
  const int t = threadIdx.x;
  const int bx = t & 63;
  const int by = blockIdx.x * 4 + (t >> 6);

  const float mean = stats[c] / M_ELEMS;
  const float var  = stats[64 + c] / M_ELEMS - mean * mean;
  const float inv  = rsqrtf(var + 1e-5f);
  const float g    = gamma[c] * inv;
  const float bb   = beta[c] - mean * g;

  const int base = ((n * 128 + c) * NPIX) + (by * 4) * 256 + bx * 4;

  float v[16];
#pragma unroll
  for (int r = 0; r < 4; ++r) {
    float4 q = *reinterpret_cast<const float4*>(&out[base + r * 256]);
    v[r * 4 + 0] = fmaxf(q.x * g + bb, 0.0f);
    v[r * 4 + 1] = fmaxf(q.y * g + bb, 0.0f);
    v[r * 4 + 2] = fmaxf(q.z * g + bb, 0.0f);
    v[r * 4 + 3] = fmaxf(q.w * g + bb, 0.0f);
  }
#pragma unroll
  for (int r = 0; r < 4; ++r) {
    float4 q;
    q.x = v[r * 4 + 0]; q.y = v[r * 4 + 1]; q.z = v[r * 4 + 2]; q.w = v[r * 4 + 3];
    *reinterpret_cast<float4*>(&out[base + r * 256]) = q;
  }
#pragma unroll
  for (int k = 2; k <= 16; k <<= 1) {
#pragma unroll
    for (int j = k >> 1; j > 0; j >>= 1) {
#pragma unroll
      for (int i = 0; i < 16; ++i) {
        int l = i ^ j;
        if (l > i) {
          bool up = ((i & k) == 0);
          float a = v[i], b = v[l];
          float mn = fminf(a, b), mx = fmaxf(a, b);
          v[i] = up ? mn : mx;
          v[l] = up ? mx : mn;
        }
      }
    }
  }
  const int ybase = base + 64 * NPIX;
#pragma unroll
  for (int r = 0; r < 4; ++r) {
    float4 q;
    q.x = v[r * 4 + 0]; q.y = v[r * 4 + 1]; q.z = v[r * 4 + 2]; q.w = v[r * 4 + 3];
    *reinterpret_cast<float4*>(&out[ybase + r * 256]) = q;
  }
}

extern "C" void kernel_launch(void* const* d_in, const int* in_sizes, int n_in,
                              void* d_out, int out_size, void* d_ws, size_t ws_size,
                              hipStream_t stream) {
  const float* x      = (const float*)d_in[0];
  const float* conv_w = (const float*)d_in[1];
  const float* conv_b = (const float*)d_in[2];
  const float* gamma  = (const float*)d_in[3];
  const float* beta   = (const float*)d_in[4];
  float* out   = (float*)d_out;
  float* ws    = (float*)d_ws;
  float* stats = ws;
  const unsigned short* wbf = (const unsigned short*)(ws + 128);

  const size_t need = (size_t)(PARTIAL_OFF + NBLK * 128) * 4;
  float* partial = (ws_size >= need) ? (ws + PARTIAL_OFF) : nullptr;

  hipLaunchKernelGGL(prep_kernel, dim3(144), dim3(256), 0, stream, conv_w, ws);
  hipLaunchKernelGGL(conv_mfma_kernel, dim3(16, 16, 16), dim3(256), 0, stream,
                     x, wbf, conv_b, out, partial, stats);
  if (partial)
    hipLaunchKernelGGL(reduce_stats_kernel, dim3(128), dim3(256), 0, stream, partial, stats);
  else
    hipLaunchKernelGGL(stats_kernel, dim3(2048), dim3(256), 0, stream, out, stats);
  hipLaunchKernelGGL(bn_sort_kernel, dim3(16, 64, 16), dim3(256), 0, stream,
                     stats, gamma, beta, out);
}

// Round 3
// 917.030 us; speedup vs baseline: 2.9430x; 1.0755x over previous
//
#include <hip/hip_runtime.h>

// x: (16,64,256,256) f32; conv_w: (64,64,3,3); conv_b/gamma/beta: (64,)
// out: (16,128,256,256) f32 -> ch 0..63 = a (BN+ReLU of conv), 64..127 = 4x4-block-sorted a
//
// ws layout (float units):
//   [0,128)            stats (sum[64], sumsq[64])
//   [128, 18560)       W' bf16 ushort[64*576], k = tap*64+ci
//   [18560, 542848)    per-block stat partials [4096][128]
//   [544768, ...)      bf16 conv output ushort[16*64*65536]  (134 MB, optional)

typedef __attribute__((ext_vector_type(8))) short short8;
typedef __attribute__((ext_vector_type(4))) float f32x4;

#define NPIX 65536
#define M_ELEMS 1048576.0f
#define PARTIAL_OFF 18560
#define NBLK 4096
#define CONVBF_OFF 544768

__device__ __forceinline__ unsigned short f2bf(float f) {
  unsigned u = __builtin_bit_cast(unsigned, f);
  u = (u + 0x7fffu + ((u >> 16) & 1u)) >> 16;
  return (unsigned short)u;
}
__device__ __forceinline__ float bf2f(unsigned short h) {
  unsigned u = ((unsigned)h) << 16;
  return __builtin_bit_cast(float, u);
}

// ---------------- K0: zero stats + build W' bf16 [cout][tap*64+ci] ----------------
__global__ __launch_bounds__(256) void prep_kernel(const float* __restrict__ w,
                                                   float* __restrict__ ws) {
  int idx = blockIdx.x * 256 + threadIdx.x;
  if (idx < 128) ws[idx] = 0.0f;
  if (idx < 36864) {
    int cout = idx / 576;
    int k    = idx % 576;
    int tap  = k >> 6;
    int ci   = k & 63;
    unsigned short* wbf = (unsigned short*)(ws + 128);
    wbf[idx] = f2bf(w[(cout * 64 + ci) * 9 + tap]);
  }
}

// ---------------- K1: implicit-GEMM MFMA conv + bias + fused stats ----------------
// 1-D grid 4096 (XCD-swizzled). 256 thr = 4 waves. Tile 16x16 pixels, 64 couts.
// Wave: 32 couts x 8 rows. K loop outer (A streamed from L2), acc persistent.
__global__ __launch_bounds__(256) void conv_mfma_kernel(
    const float* __restrict__ x, const unsigned short* __restrict__ wbf,
    const float* __restrict__ bias, float* __restrict__ out,
    unsigned short* __restrict__ convbf,
    float* __restrict__ partial, float* __restrict__ stats) {
  __shared__ short sX[400 * 64];   // 51200 B, layout [pix][ci] with ci-block XOR swizzle
  __shared__ float sRed[2][128];

  const int t    = threadIdx.x;
  const int lane = t & 63;
  const int wv   = t >> 6;
  const int g    = lane >> 4;      // k-group
  const int px   = lane & 15;      // pixel col / B col
  // XCD swizzle: XCD k owns contiguous original ids [k*512,(k+1)*512) = 2 batch images
  const int bid  = blockIdx.x;
  const int swz  = (bid & 7) * 512 + (bid >> 3);
  const int n    = swz >> 8;
  const int h0   = ((swz >> 4) & 15) * 16;
  const int w0   = (swz & 15) * 16;

  const int cbase  = (wv & 1) * 32;
  const int pybase = (wv >> 1) * 8;

  // ---- stage X tile (zero-padded halo) into LDS as bf16, swizzled ----
  for (int cg = 0; cg < 8; ++cg) {
    const float* xc = x + (size_t)(n * 64 + cg * 8) * NPIX;
#pragma unroll
    for (int b = 0; b < 2; ++b) {
      int pix = b * 256 + t;
      if (pix < 400) {
        int hy = pix / 20, hx = pix - hy * 20;
        int h = h0 + hy - 2, w = w0 + hx - 2;
        short8 pk;
        if ((unsigned)h < 256u && (unsigned)w < 256u) {
          const float* xp = xc + h * 256 + w;
#pragma unroll
          for (int j = 0; j < 8; ++j) pk[j] = (short)f2bf(xp[j * NPIX]);
        } else {
#pragma unroll
          for (int j = 0; j < 8; ++j) pk[j] = 0;
        }
        int blkS = cg ^ (pix & 7);
        *reinterpret_cast<short8*>(&sX[pix * 64 + blkS * 8]) = pk;
      }
    }
  }
  __syncthreads();

  f32x4 acc0[8], acc1[8];
#pragma unroll
  for (int i = 0; i < 8; ++i) {
    acc0[i] = (f32x4){0.f, 0.f, 0.f, 0.f};
    acc1[i] = (f32x4){0.f, 0.f, 0.f, 0.f};
  }

  const unsigned short* abase = wbf + (cbase + px) * 576 + g * 8;
  short8 a0c = *reinterpret_cast<const short8*>(abase);
  short8 a1c = *reinterpret_cast<const short8*>(abase + 16 * 576);

#pragma unroll 1
  for (int s = 0; s < 18; ++s) {
    short8 a0n = a0c, a1n = a1c;
    if (s < 17) {
      a0n = *reinterpret_cast<const short8*>(abase + (s + 1) * 32);
      a1n = *reinterpret_cast<const short8*>(abase + 16 * 576 + (s + 1) * 32);
    }
    const int tap = s >> 1;
    const int dy2 = (tap * 11) >> 5;          // tap/3
    const int dxh = tap - dy2 * 3;            // tap%3
    const int pixbase = (pybase + dy2 * 2) * 20 + px + dxh * 2;
    const int blkbase = (s & 1) * 4 + g;
#pragma unroll
    for (int py = 0; py < 8; ++py) {
      int pix = pixbase + py * 20;
      int blk = blkbase ^ (pix & 7);
      short8 bf = *reinterpret_cast<const short8*>(&sX[pix * 64 + blk * 8]);
      acc0[py] = __builtin_amdgcn_mfma_f32_16x16x32_bf16(a0c, bf, acc0[py], 0, 0, 0);
      acc1[py] = __builtin_amdgcn_mfma_f32_16x16x32_bf16(a1c, bf, acc1[py], 0, 0, 0);
    }
    a0c = a0n;
    a1c = a1n;
  }

  float b0[4], b1[4];
#pragma unroll
  for (int i = 0; i < 4; ++i) {
    b0[i] = bias[cbase + g * 4 + i];
    b1[i] = bias[cbase + 16 + g * 4 + i];
  }
  float lsum[8] = {0, 0, 0, 0, 0, 0, 0, 0};
  float lsq[8]  = {0, 0, 0, 0, 0, 0, 0, 0};

  // C/D layout: col = lane&15 (pixel), row = (lane>>4)*4 + i (cout in 16-tile)
#pragma unroll
  for (int py = 0; py < 8; ++py) {
    const int h = h0 + pybase + py, wo = w0 + px;
#pragma unroll
    for (int i = 0; i < 4; ++i) {
      float v0 = acc0[py][i] + b0[i];
      float v1 = acc1[py][i] + b1[i];
      int c0 = cbase + g * 4 + i, c1 = c0 + 16;
      if (convbf) {
        unsigned short u0 = f2bf(v0), u1 = f2bf(v1);
        convbf[(size_t)(n * 64 + c0) * NPIX + h * 256 + wo] = u0;
        convbf[(size_t)(n * 64 + c1) * NPIX + h * 256 + wo] = u1;
        v0 = bf2f(u0); v1 = bf2f(u1);   // stats of the stored (rounded) values
      } else {
        out[(size_t)(n * 128 + c0) * NPIX + h * 256 + wo] = v0;
        out[(size_t)(n * 128 + c1) * NPIX + h * 256 + wo] = v1;
      }
      lsum[i] += v0;     lsq[i] += v0 * v0;
      lsum[4 + i] += v1; lsq[4 + i] += v1 * v1;
    }
  }

  // ---- fused stats: reduce across the 16 lanes sharing the same couts ----
#pragma unroll
  for (int m = 1; m < 16; m <<= 1) {
#pragma unroll
    for (int k = 0; k < 8; ++k) {
      lsum[k] += __shfl_xor(lsum[k], m);
      lsq[k]  += __shfl_xor(lsq[k], m);
    }
  }
  const int ph = wv >> 1;
  if ((lane & 15) == 0) {
#pragma unroll
    for (int i = 0; i < 4; ++i) {
      int c0 = cbase + g * 4 + i, c1 = c0 + 16;
      sRed[ph][c0] = lsum[i];     sRed[ph][64 + c0] = lsq[i];
      sRed[ph][c1] = lsum[4 + i]; sRed[ph][64 + c1] = lsq[4 + i];
    }
  }
  __syncthreads();
  if (t < 128) {
    float v = sRed[0][t] + sRed[1][t];
    if (partial) partial[(size_t)bid * 128 + t] = v;
    else         atomicAdd(&stats[t], v);
  }
}

// ---------------- K2a: coalesced reduce of partials -> stats ----------------
// 128 blocks; block b sums bids [b*32, b*32+32). Lanes 0..127 read one 512B row.
__global__ __launch_bounds__(256) void reduce_stats_kernel(const float* __restrict__ partial,
                                                           float* __restrict__ stats) {
  __shared__ float red[128];
  const int t = threadIdx.x;
  const int c = t & 127;
  const int half = t >> 7;
  float s = 0.f;
#pragma unroll
  for (int j = 0; j < 16; ++j)
    s += partial[(size_t)(blockIdx.x * 32 + half * 16 + j) * 128 + c];
  if (half == 1) red[c] = s;
  __syncthreads();
  if (half == 0) atomicAdd(&stats[c], s + red[c]);
}

// ---------------- K2b fallback: per-channel sum/sumsq over a-region (f32) ----------------
__global__ __launch_bounds__(256) void stats_kernel(const float* __restrict__ convOut,
                                                    float* __restrict__ stats) {
  const int c    = blockIdx.x >> 5;
  const int part = blockIdx.x & 31;
  const int n    = part >> 1;
  const int half = part & 1;
  const float* base = convOut + ((size_t)(n * 128 + c)) * NPIX + half * 32768;
  float s = 0.0f, sq = 0.0f;
#pragma unroll 4
  for (int i = 0; i < 32; ++i) {
    float4 v = *reinterpret_cast<const float4*>(base + i * 1024 + threadIdx.x * 4);
    s  += v.x + v.y + v.z + v.w;
    sq += v.x * v.x + v.y * v.y + v.z * v.z + v.w * v.w;
  }
#pragma unroll
  for (int off = 32; off > 0; off >>= 1) {
    s  += __shfl_down(s, off);
    sq += __shfl_down(sq, off);
  }
  __shared__ float ls[4], lq[4];
  int wid = threadIdx.x >> 6, lane = threadIdx.x & 63;
  if (lane == 0) { ls[wid] = s; lq[wid] = sq; }
  __syncthreads();
  if (threadIdx.x == 0) {
    atomicAdd(&stats[c], ls[0] + ls[1] + ls[2] + ls[3]);
    atomicAdd(&stats[64 + c], lq[0] + lq[1] + lq[2] + lq[3]);
  }
}

// ---------------- K3: BN + ReLU + 4x4 block sort -> a and y ----------------
__global__ __launch_bounds__(256) void bn_sort_kernel(const float* __restrict__ stats,
                                                      const float* __restrict__ gamma,
                                                      const float* __restrict__ beta,
                                                      float* __restrict__ out,
                                                      const unsigned short* __restrict__ srcbf) {
  const int c = blockIdx.y;
  const int n = blockIdx.z;
  const int t = threadIdx.x;
  const int bx = t & 63;
  const int by = blockIdx.x * 4 + (t >> 6);

  const float mean = stats[c] / M_ELEMS;
  const float var  = stats[64 + c] / M_ELEMS - mean * mean;
  const float inv  = rsqrtf(var + 1e-5f);
  const float g    = gamma[c] * inv;
  const float bb   = beta[c] - mean * g;

  const int base = ((n * 128 + c) * NPIX) + (by * 4) * 256 + bx * 4;

  float v[16];
  if (srcbf) {
    const unsigned short* sb = srcbf + (size_t)(n * 64 + c) * NPIX + (by * 4) * 256 + bx * 4;
#pragma unroll
    for (int r = 0; r < 4; ++r) {
      ushort4 q = *reinterpret_cast<const ushort4*>(sb + r * 256);
      v[r * 4 + 0] = fmaxf(bf2f(q.x) * g + bb, 0.0f);
      v[r * 4 + 1] = fmaxf(bf2f(q.y) * g + bb, 0.0f);
      v[r * 4 + 2] = fmaxf(bf2f(q.z) * g + bb, 0.0f);
      v[r * 4 + 3] = fmaxf(bf2f(q.w) * g + bb, 0.0f);
    }
  } else {
#pragma unroll
    for (int r = 0; r < 4; ++r) {
      float4 q = *reinterpret_cast<const float4*>(&out[base + r * 256]);
      v[r * 4 + 0] = fmaxf(q.x * g + bb, 0.0f);
      v[r * 4 + 1] = fmaxf(q.y * g + bb, 0.0f);
      v[r * 4 + 2] = fmaxf(q.z * g + bb, 0.0f);
      v[r * 4 + 3] = fmaxf(q.w * g + bb, 0.0f);
    }
  }
#pragma unroll
  for (int r = 0; r < 4; ++r) {
    float4 q;
    q.x = v[r * 4 + 0]; q.y = v[r * 4 + 1]; q.z = v[r * 4 + 2]; q.w = v[r * 4 + 3];
    *reinterpret_cast<float4*>(&out[base + r * 256]) = q;
  }
#pragma unroll
  for (int k = 2; k <= 16; k <<= 1) {
#pragma unroll
    for (int j = k >> 1; j > 0; j >>= 1) {
#pragma unroll
      for (int i = 0; i < 16; ++i) {
        int l = i ^ j;
        if (l > i) {
          bool up = ((i & k) == 0);
          float a = v[i], b = v[l];
          float mn = fminf(a, b), mx = fmaxf(a, b);
          v[i] = up ? mn : mx;
          v[l] = up ? mx : mn;
        }
      }
    }
  }
  const int ybase = base + 64 * NPIX;
#pragma unroll
  for (int r = 0; r < 4; ++r) {
    float4 q;
    q.x = v[r * 4 + 0]; q.y = v[r * 4 + 1]; q.z = v[r * 4 + 2]; q.w = v[r * 4 + 3];
    *reinterpret_cast<float4*>(&out[ybase + r * 256]) = q;
  }
}

extern "C" void kernel_launch(void* const* d_in, const int* in_sizes, int n_in,
                              void* d_out, int out_size, void* d_ws, size_t ws_size,
                              hipStream_t stream) {
  const float* x      = (const float*)d_in[0];
  const float* conv_w = (const float*)d_in[1];
  const float* conv_b = (const float*)d_in[2];
  const float* gamma  = (const float*)d_in[3];
  const float* beta   = (const float*)d_in[4];
  float* out   = (float*)d_out;
  float* ws    = (float*)d_ws;
  float* stats = ws;
  const unsigned short* wbf = (const unsigned short*)(ws + 128);

  const size_t needPartial = (size_t)(PARTIAL_OFF + NBLK * 128) * 4;
  const size_t needBf = ((size_t)CONVBF_OFF + 33554432ull) * 4;  // ~136.4 MB
  float* partial = (ws_size >= needPartial) ? (ws + PARTIAL_OFF) : nullptr;
  unsigned short* convbf = (ws_size >= needBf) ? (unsigned short*)(ws + CONVBF_OFF) : nullptr;

  hipLaunchKernelGGL(prep_kernel, dim3(144), dim3(256), 0, stream, conv_w, ws);
  hipLaunchKernelGGL(conv_mfma_kernel, dim3(4096), dim3(256), 0, stream,
                     x, wbf, conv_b, out, convbf, partial, stats);
  if (partial)
    hipLaunchKernelGGL(reduce_stats_kernel, dim3(128), dim3(256), 0, stream, partial, stats);
  else
    hipLaunchKernelGGL(stats_kernel, dim3(2048), dim3(256), 0, stream, out, stats);
  hipLaunchKernelGGL(bn_sort_kernel, dim3(16, 64, 16), dim3(256), 0, stream,
                     stats, gamma, beta, out, (const unsigned short*)convbf);
}